// Round 5
// baseline (451.263 us; speedup 1.0000x reference)
//
#include <hip/hip_runtime.h>
#include <cstddef>
#include <cstdint>

#define THRESH 0.8f
#define DECAY  0.2f

typedef unsigned short ushort_t;
typedef __attribute__((ext_vector_type(8))) short bf16x8;
typedef __attribute__((ext_vector_type(4))) float f32x4;

__device__ __forceinline__ ushort_t f2bf(float f) {
    union { float f; unsigned u; } v; v.f = f;
    unsigned r = v.u + 0x7FFFu + ((v.u >> 16) & 1u);
    return (ushort_t)(r >> 16);
}
__device__ __forceinline__ float bf2f(ushort_t h) {
    union { unsigned u; float f; } v; v.u = ((unsigned)h) << 16;
    return v.f;
}
__device__ __forceinline__ float blo(unsigned u) {
    union { unsigned x; float f; } v; v.x = u << 16; return v.f;
}
__device__ __forceinline__ float bhi(unsigned u) {
    union { unsigned x; float f; } v; v.x = u & 0xFFFF0000u; return v.f;
}

// async global->LDS, 16B per lane; LDS dest = wave-uniform base + lane*16
__device__ __forceinline__ void gload16(const void* g, void* l) {
    __builtin_amdgcn_global_load_lds(
        (const __attribute__((address_space(1))) void*)g,
        (__attribute__((address_space(3))) void*)l,
        16, 0, 0);
}

// ---------------------------------------------------------------------------
// FUSED currents GEMM + LIF recurrence.
// Block tile: 64 batches (= 320 A rows, b*5+f) x 32 channels (= 96 W rows:
// w1|w2|w3 row-groups of 32).  512 threads = 8 waves arranged 4(m) x 2(n):
// per-wave 80 rows (5 m-tiles) x 48 cols (3 n-tiles), 16x16x32 bf16 MFMA,
// NSPLIT=3 hi/lo split (hh + hl + lh) for near-fp32 currents.
// Epilogue: per 80-row quarter (16 whole batches), accs bounce through LDS
// (30KB overlay on staging buffers), 512 threads run the 15-step recurrence
// (1 thread = 1 (b,c) pair) and write x bf16 [2048,4096] directly.
// Saves the 126MB cur write + 126MB recur read of the unfused version.
// ---------------------------------------------------------------------------
__global__ __launch_bounds__(512) void cur_recur_fused(
    const ushort_t* __restrict__ Ah, const ushort_t* __restrict__ Al,
    const ushort_t* __restrict__ Wh, const ushort_t* __restrict__ Wl,
    const float* __restrict__ b123, const float* __restrict__ wl,
    const float* __restrict__ bl, ushort_t* __restrict__ x)
{
    // [A hi: 20*512][A lo: 20*512][W hi: 6*512][W lo: 6*512] ushorts = 53.2KB
    __shared__ ushort_t smem[26624];
    ushort_t* sAh = smem;
    ushort_t* sAl = smem + 10240;
    ushort_t* sWh = smem + 20480;
    ushort_t* sWl = smem + 23552;

    const int t = threadIdx.x;
    const int lane = t & 63;
    const int wv = t >> 6;
    const int cBase = blockIdx.x * 32;   // x fast-varying: A-tile L2 reuse
    const int bBase = blockIdx.y * 64;
    const int aRow0 = bBase * 5;

    const int mg = wv & 3;               // m-group: rows [mg*80, mg*80+80)
    const int ng = wv >> 2;              // n-group: cols [ng*48, ng*48+48)
    const int fr = lane & 15;
    const int fq = lane >> 4;
    const int rlane = lane >> 2;
    const int klane = (lane & 3) * 8;

    f32x4 acc[5][3];
#pragma unroll
    for (int i = 0; i < 5; i++)
#pragma unroll
        for (int j = 0; j < 3; j++) {
            f32x4 z = {0.f, 0.f, 0.f, 0.f};
            acc[i][j] = z;
        }

    for (int k0 = 0; k0 < 512; k0 += 32) {
        // 52 1KB staging segments (A hi 20, A lo 20, W hi 6, W lo 6),
        // round-robin across 8 waves
        for (int s = wv; s < 52; s += 8) {
            if (s < 40) {
                const int ss = (s < 20) ? s : s - 20;
                const ushort_t* src = (s < 20) ? Ah : Al;
                ushort_t* dst = (s < 20) ? sAh : sAl;
                const int row = aRow0 + ss * 16 + rlane;
                gload16(&src[(size_t)row * 512 + k0 + klane], &dst[ss * 512 + lane * 8]);
            } else {
                const int ss = (s < 46) ? s - 40 : s - 46;
                const ushort_t* src = (s < 46) ? Wh : Wl;
                ushort_t* dst = (s < 46) ? sWh : sWl;
                const int wrow = ss * 16 + rlane;
                const int row = (wrow >> 5) * 1024 + cBase + (wrow & 31);
                gload16(&src[(size_t)row * 512 + k0 + klane], &dst[ss * 512 + lane * 8]);
            }
        }
        __syncthreads();

        bf16x8 wf[3][2];
#pragma unroll
        for (int j = 0; j < 3; j++) {
            wf[j][0] = *(const bf16x8*)&sWh[(ng * 48 + j * 16 + fr) * 32 + fq * 8];
            wf[j][1] = *(const bf16x8*)&sWl[(ng * 48 + j * 16 + fr) * 32 + fq * 8];
        }
#pragma unroll
        for (int i = 0; i < 5; i++) {
            const bf16x8 ah = *(const bf16x8*)&sAh[(mg * 80 + i * 16 + fr) * 32 + fq * 8];
            const bf16x8 al = *(const bf16x8*)&sAl[(mg * 80 + i * 16 + fr) * 32 + fq * 8];
#pragma unroll
            for (int j = 0; j < 3; j++) {
                acc[i][j] = __builtin_amdgcn_mfma_f32_16x16x32_bf16(ah, wf[j][0], acc[i][j], 0, 0, 0);
                acc[i][j] = __builtin_amdgcn_mfma_f32_16x16x32_bf16(ah, wf[j][1], acc[i][j], 0, 0, 0);
                acc[i][j] = __builtin_amdgcn_mfma_f32_16x16x32_bf16(al, wf[j][0], acc[i][j], 0, 0, 0);
            }
        }
        __syncthreads();
    }

    // ---- fused recurrence epilogue ----
    float* buf = (float*)smem;           // 80 x 96 fp32 = 30.7KB (fits 53.2KB)
    const float wl0 = wl[0], wl1 = wl[1], wl2 = wl[2], bl0 = bl[0];
    const int lb = t >> 5;               // local batch 0..15
    const int lc = t & 31;               // local channel 0..31
    const float bv0 = b123[cBase + lc];
    const float bv1 = b123[1024 + cBase + lc];
    const float bv2 = b123[2048 + cBase + lc];
    const float inv15 = 1.0f / 15.0f;

    for (int q = 0; q < 4; q++) {
        if (mg == q) {
            // dump this quarter's accs: C/D layout row=(fq*4+r), col=fr per tile
#pragma unroll
            for (int i = 0; i < 5; i++)
#pragma unroll
                for (int j = 0; j < 3; j++)
#pragma unroll
                    for (int r = 0; r < 4; r++)
                        buf[(i * 16 + fq * 4 + r) * 96 + ng * 48 + j * 16 + fr] = acc[i][j][r];
        }
        __syncthreads();

        float m0 = 0, m1 = 0, m2 = 0, m3 = 0;
        float s0 = 0, s1 = 0, s2 = 0, s3 = 0;
#pragma unroll
        for (int f = 0; f < 5; f++) {
            const float* p = &buf[(lb * 5 + f) * 96 + lc];
            const float i1 = p[0] + bv0;
            const float i2 = p[32] + bv1;
            const float i3 = p[64] + bv2;
#pragma unroll
            for (int rep = 0; rep < 3; rep++) {
                const float inner = m0 * wl0 + m1 * wl1 + m2 * wl2 + bl0;
                const float n0 = i1 + ((m0 > THRESH) ? 0.f : DECAY * m0);
                const float n1 = i2 + ((m1 > THRESH) ? 0.f : DECAY * m1);
                const float n2 = i3 + ((m2 > THRESH) ? 0.f : DECAY * m2);
                const float n3 = inner + ((m3 > THRESH) ? 0.f : DECAY * m3);
                m0 = n0; m1 = n1; m2 = n2; m3 = n3;
                s0 += (n0 > THRESH) ? 1.f : 0.f;
                s1 += (n1 > THRESH) ? 1.f : 0.f;
                s2 += (n2 > THRESH) ? 1.f : 0.f;
                s3 += (n3 > THRESH) ? 1.f : 0.f;
            }
        }
        ushort4 o;
        o.x = f2bf(s0 * inv15); o.y = f2bf(s1 * inv15);
        o.z = f2bf(s2 * inv15); o.w = f2bf(s3 * inv15);
        *(ushort4*)&x[(size_t)(bBase + q * 16 + lb) * 4096 + (cBase + lc) * 4] = o;
        __syncthreads();
    }
}

// ---------------------------------------------------------------------------
// MLP GEMM: 256-thread (4-wave), 128x128 tile, per-wave 64x64 (4x4 frags),
// BK=32, plain bf16.  Split-K via blockIdx.z (K = per-slice length, partial
// fp32 out at C + z*sliceStride).  aHalfOff: block-diagonal A col offset.
// ---------------------------------------------------------------------------
__global__ __launch_bounds__(256) void mlp_gemm256(
    const ushort_t* __restrict__ A, const ushort_t* __restrict__ W,
    float* __restrict__ C,
    int N, int K, int lda, int ldw, int ldc, int aHalfOff,
    size_t sliceStride)
{
    __shared__ ushort_t sA[128 * 32];
    __shared__ ushort_t sW[128 * 32];

    const int t = threadIdx.x;
    const int mBase = blockIdx.x * 128;
    const int nBase = blockIdx.y * 128;
    const int kOff = blockIdx.z * K;
    const int aOff = (2 * nBase >= N) ? aHalfOff : 0;
    float* Cz = C + (size_t)blockIdx.z * sliceStride;

    const int lane = t & 63;
    const int wv = t >> 6;
    const int wm = (wv & 1) * 64;
    const int wn = (wv >> 1) * 64;
    const int fr = lane & 15;
    const int fq = lane >> 4;

    const int r0 = t >> 2;               // 0..63
    const int cc = (t & 3) * 8;

    f32x4 acc[4][4];
#pragma unroll
    for (int i = 0; i < 4; i++)
#pragma unroll
        for (int j = 0; j < 4; j++) {
            f32x4 z = {0.f, 0.f, 0.f, 0.f};
            acc[i][j] = z;
        }

    for (int k0 = 0; k0 < K; k0 += 32) {
        gload16(&A[(size_t)(mBase + r0) * lda + aOff + kOff + k0 + cc], &sA[t * 8]);
        gload16(&A[(size_t)(mBase + 64 + r0) * lda + aOff + kOff + k0 + cc], &sA[2048 + t * 8]);
        gload16(&W[(size_t)(nBase + r0) * ldw + kOff + k0 + cc], &sW[t * 8]);
        gload16(&W[(size_t)(nBase + 64 + r0) * ldw + kOff + k0 + cc], &sW[2048 + t * 8]);
        __syncthreads();

        bf16x8 af[4], wf[4];
#pragma unroll
        for (int i = 0; i < 4; i++) {
            af[i] = *(const bf16x8*)&sA[(wm + i * 16 + fr) * 32 + fq * 8];
            wf[i] = *(const bf16x8*)&sW[(wn + i * 16 + fr) * 32 + fq * 8];
        }
#pragma unroll
        for (int i = 0; i < 4; i++)
#pragma unroll
            for (int j = 0; j < 4; j++)
                acc[i][j] = __builtin_amdgcn_mfma_f32_16x16x32_bf16(af[i], wf[j], acc[i][j], 0, 0, 0);
        __syncthreads();
    }

#pragma unroll
    for (int j = 0; j < 4; j++) {
        const int col = nBase + wn + j * 16 + fr;
#pragma unroll
        for (int i = 0; i < 4; i++)
#pragma unroll
            for (int r = 0; r < 4; r++) {
                const int row = mBase + wm + i * 16 + fq * 4 + r;
                Cz[(size_t)row * ldc + col] = acc[i][j][r];
            }
    }
}

// ---------------------------------------------------------------------------
// split-K reduce: out_bf16[m][n] = relu(sum_s part[s][m][n] + bias[n])
// ---------------------------------------------------------------------------
template <int S>
__global__ __launch_bounds__(256) void reduce_relu(
    const float* __restrict__ part, const float* __restrict__ bias,
    ushort_t* __restrict__ out, int N, size_t MN)
{
    const size_t stride = (size_t)gridDim.x * 1024;
    for (size_t e = ((size_t)blockIdx.x * 256 + threadIdx.x) * 4; e < MN; e += stride) {
        float4 a = *(const float4*)&part[e];
#pragma unroll
        for (int s = 1; s < S; s++) {
            const float4 b = *(const float4*)&part[s * MN + e];
            a.x += b.x; a.y += b.y; a.z += b.z; a.w += b.w;
        }
        const int n = (int)(e & (size_t)(N - 1));
        const float4 bv = *(const float4*)&bias[n];
        ushort4 o;
        o.x = f2bf(fmaxf(a.x + bv.x, 0.f));
        o.y = f2bf(fmaxf(a.y + bv.y, 0.f));
        o.z = f2bf(fmaxf(a.z + bv.z, 0.f));
        o.w = f2bf(fmaxf(a.w + bv.w, 0.f));
        *(ushort4*)&out[e] = o;
    }
}

// ---------------------------------------------------------------------------
// Consolidated prep (4 float4s per thread per segment block)
// ---------------------------------------------------------------------------
__device__ __forceinline__ void do_split4(const float4* src, ushort4* hi,
                                          ushort4* lo, int base, int t) {
#pragma unroll
    for (int p = 0; p < 4; p++) {
        const int i = base * 1024 + p * 256 + t;
        const float4 v = src[i];
        ushort4 h, l;
        h.x = f2bf(v.x); l.x = f2bf(v.x - bf2f(h.x));
        h.y = f2bf(v.y); l.y = f2bf(v.y - bf2f(h.y));
        h.z = f2bf(v.z); l.z = f2bf(v.z - bf2f(h.z));
        h.w = f2bf(v.w); l.w = f2bf(v.w - bf2f(h.w));
        hi[i] = h; lo[i] = l;
    }
}
__device__ __forceinline__ void do_cvt4(const float4* src, ushort4* dst,
                                        int base, int t) {
#pragma unroll
    for (int p = 0; p < 4; p++) {
        const int i = base * 1024 + p * 256 + t;
        const float4 v = src[i];
        ushort4 h;
        h.x = f2bf(v.x); h.y = f2bf(v.y); h.z = f2bf(v.z); h.w = f2bf(v.w);
        dst[i] = h;
    }
}

__global__ __launch_bounds__(256) void prep_kernel(
    const float* __restrict__ state,
    const float* __restrict__ w1, const float* __restrict__ w2,
    const float* __restrict__ w3,
    const float* __restrict__ w11, const float* __restrict__ w21,
    const float* __restrict__ w12, const float* __restrict__ w22,
    const float* __restrict__ b1, const float* __restrict__ b2,
    const float* __restrict__ b3, const float* __restrict__ b11,
    const float* __restrict__ b21, const float* __restrict__ b12,
    const float* __restrict__ b22,
    ushort_t* __restrict__ sh, ushort_t* __restrict__ sl,
    ushort_t* __restrict__ wh123, ushort_t* __restrict__ wl123,
    ushort_t* __restrict__ w1b, ushort_t* __restrict__ w2b,
    float* __restrict__ b123, float* __restrict__ bb1, float* __restrict__ bb2)
{
    const int bid = blockIdx.x;
    const int t = threadIdx.x;
    if (bid < 1280) {
        do_split4((const float4*)state, (ushort4*)sh, (ushort4*)sl, bid, t);
    } else if (bid < 1408) {
        do_split4((const float4*)w1, (ushort4*)wh123, (ushort4*)wl123, bid - 1280, t);
    } else if (bid < 1536) {
        do_split4((const float4*)w2, (ushort4*)(wh123 + 524288),
                  (ushort4*)(wl123 + 524288), bid - 1408, t);
    } else if (bid < 1664) {
        do_split4((const float4*)w3, (ushort4*)(wh123 + 1048576),
                  (ushort4*)(wl123 + 1048576), bid - 1536, t);
    } else if (bid < 2688) {
        do_cvt4((const float4*)w11, (ushort4*)w1b, bid - 1664, t);
    } else if (bid < 3712) {
        do_cvt4((const float4*)w21, (ushort4*)(w1b + 4194304), bid - 2688, t);
    } else if (bid < 3968) {
        do_cvt4((const float4*)w12, (ushort4*)w2b, bid - 3712, t);
    } else if (bid < 4224) {
        do_cvt4((const float4*)w22, (ushort4*)(w2b + 1048576), bid - 3968, t);
    } else {
#pragma unroll
        for (int p = 0; p < 4; p++) {
            const int i = p * 256 + t;
            b123[i] = b1[i]; b123[1024 + i] = b2[i]; b123[2048 + i] = b3[i];
            bb1[i] = b11[i]; bb1[1024 + i] = b21[i];
            bb2[i] = b12[i]; bb2[1024 + i] = b22[i];
        }
    }
}

// ---------------------------------------------------------------------------
// Heads (both branches): out[b][n] = (clip?)(h2[b][off+k] . w[n][k] + bias[n])
// ---------------------------------------------------------------------------
__global__ __launch_bounds__(256) void head_kernel(
    const ushort_t* __restrict__ h, const float* __restrict__ wm,
    const float* __restrict__ bm, const float* __restrict__ ws,
    const float* __restrict__ bs, float* __restrict__ out)
{
    const int t = threadIdx.x;
    const int branch = blockIdx.x >> 8;
    const int n = t & 31;
    const int b = (blockIdx.x & 255) * 8 + (t >> 5);
    const ushort_t* hr = h + (size_t)b * 2048 + branch * 1024;
    const float* wr = (branch ? ws : wm) + (size_t)n * 1024;
    float s = 0.f;
#pragma unroll 4
    for (int k = 0; k < 1024; k += 8) {
        const uint4 hv = *(const uint4*)&hr[k];
        const float4 w0 = *(const float4*)&wr[k];
        const float4 w1 = *(const float4*)&wr[k + 4];
        s += blo(hv.x) * w0.x + bhi(hv.x) * w0.y
           + blo(hv.y) * w0.z + bhi(hv.y) * w0.w
           + blo(hv.z) * w1.x + bhi(hv.z) * w1.y
           + blo(hv.w) * w1.z + bhi(hv.w) * w1.w;
    }
    s += (branch ? bs : bm)[n];
    if (branch) s = fminf(fmaxf(s, -20.f), 2.f);
    out[(size_t)branch * 65536 + (size_t)b * 32 + n] = s;
}

// ---------------------------------------------------------------------------
extern "C" void kernel_launch(void* const* d_in, const int* in_sizes, int n_in,
                              void* d_out, int out_size, void* d_ws, size_t ws_size,
                              hipStream_t stream)
{
    const float* state = (const float*)d_in[0];
    const float* w1  = (const float*)d_in[1];  const float* b1  = (const float*)d_in[2];
    const float* w2  = (const float*)d_in[3];  const float* b2  = (const float*)d_in[4];
    const float* w3  = (const float*)d_in[5];  const float* b3  = (const float*)d_in[6];
    const float* wl  = (const float*)d_in[7];  const float* bl  = (const float*)d_in[8];
    const float* w11 = (const float*)d_in[9];  const float* b11 = (const float*)d_in[10];
    const float* w12 = (const float*)d_in[11]; const float* b12 = (const float*)d_in[12];
    const float* w21 = (const float*)d_in[13]; const float* b21 = (const float*)d_in[14];
    const float* w22 = (const float*)d_in[15]; const float* b22 = (const float*)d_in[16];
    const float* wm  = (const float*)d_in[17]; const float* bm  = (const float*)d_in[18];
    const float* ws  = (const float*)d_in[19]; const float* bs  = (const float*)d_in[20];
    float* out = (float*)d_out;

    // ---- workspace layout ----
    // cur region now only holds the MLP split-K partials (2 x 16.8MB)
    char* wp = (char*)d_ws;
    float*    cur   = (float*)wp;     wp += (size_t)10240 * 3072 * 4;
    ushort_t* sh    = (ushort_t*)wp;  wp += (size_t)10240 * 512 * 2;
    ushort_t* sl    = (ushort_t*)wp;  wp += (size_t)10240 * 512 * 2;
    ushort_t* wh123 = (ushort_t*)wp;  wp += (size_t)3072 * 512 * 2;
    ushort_t* wl123 = (ushort_t*)wp;  wp += (size_t)3072 * 512 * 2;
    ushort_t* xb    = (ushort_t*)wp;  wp += (size_t)2048 * 4096 * 2;
    ushort_t* w1b   = (ushort_t*)wp;  wp += (size_t)2048 * 4096 * 2;
    ushort_t* w2b   = (ushort_t*)wp;  wp += (size_t)2048 * 1024 * 2;
    ushort_t* h1    = (ushort_t*)wp;  wp += (size_t)2048 * 2048 * 2;
    ushort_t* h2    = (ushort_t*)wp;  wp += (size_t)2048 * 2048 * 2;
    float*    b123  = (float*)wp;     wp += 3072 * 4;
    float*    bb1   = (float*)wp;     wp += 2048 * 4;
    float*    bb2   = (float*)wp;     wp += 2048 * 4;

    const size_t MN = (size_t)2048 * 2048;

    // ---- prep: all splits/cvts/bias packing in one launch ----
    prep_kernel<<<4225, 256, 0, stream>>>(
        state, w1, w2, w3, w11, w21, w12, w22,
        b1, b2, b3, b11, b21, b12, b22,
        sh, sl, wh123, wl123, w1b, w2b, b123, bb1, bb2);

    // ---- fused currents GEMM + recurrence -> x bf16 [2048,4096] ----
    // grid: x = channel-group (fast, A-reuse), y = batch-group
    cur_recur_fused<<<dim3(32, 32), 512, 0, stream>>>(
        sh, sl, wh123, wl123, b123, wl, bl, xb);

    // ---- MLP layer 1 (both branches, N=2048), split-K=2 -> partials ----
    mlp_gemm256<<<dim3(16, 16, 2), 256, 0, stream>>>(
        xb, w1b, cur, 2048, 2048, 4096, 4096, 2048, 0, MN);
    reduce_relu<2><<<1024, 256, 0, stream>>>(cur, bb1, h1, 2048, MN);

    // ---- MLP layer 2 (block-diagonal), split-K=2 -> partials ----
    mlp_gemm256<<<dim3(16, 16, 2), 256, 0, stream>>>(
        h1, w2b, cur, 2048, 512, 2048, 1024, 2048, 1024, MN);
    reduce_relu<2><<<1024, 256, 0, stream>>>(cur, bb2, h2, 2048, MN);

    // ---- heads (both branches) ----
    head_kernel<<<512, 256, 0, stream>>>(h2, wm, bm, ws, bs, out);
}

// Round 6
// 421.880 us; speedup vs baseline: 1.0696x; 1.0696x over previous
//
#include <hip/hip_runtime.h>
#include <cstddef>
#include <cstdint>

#define THRESH 0.8f
#define DECAY  0.2f

typedef unsigned short ushort_t;
typedef __attribute__((ext_vector_type(8))) short bf16x8;
typedef __attribute__((ext_vector_type(4))) float f32x4;

__device__ __forceinline__ ushort_t f2bf(float f) {
    union { float f; unsigned u; } v; v.f = f;
    unsigned r = v.u + 0x7FFFu + ((v.u >> 16) & 1u);
    return (ushort_t)(r >> 16);
}
__device__ __forceinline__ float bf2f(ushort_t h) {
    union { unsigned u; float f; } v; v.u = ((unsigned)h) << 16;
    return v.f;
}
__device__ __forceinline__ float blo(unsigned u) {
    union { unsigned x; float f; } v; v.x = u << 16; return v.f;
}
__device__ __forceinline__ float bhi(unsigned u) {
    union { unsigned x; float f; } v; v.x = u & 0xFFFF0000u; return v.f;
}

// async global->LDS, 16B per lane; LDS dest = wave-uniform base + lane*16
__device__ __forceinline__ void gload16(const void* g, void* l) {
    __builtin_amdgcn_global_load_lds(
        (const __attribute__((address_space(1))) void*)g,
        (__attribute__((address_space(3))) void*)l,
        16, 0, 0);
}

// ---------------------------------------------------------------------------
// Currents GEMM: 256-thread (4-wave), 128x128 tile, per-wave 64x64 (4x4
// frags), BK=32, NSPLIT=3 hi/lo split (hh + hl + lh) for near-fp32.
// Per-iter/wave: 16 ds_read_b128 (192 cyc) per 48 MFMA (230 cyc) -> MFMA-bound
// (the 8-wave 64x32 variant was 12:24 = LDS-bound).  Grid 80x24 = 1920 blocks.
// ---------------------------------------------------------------------------
__global__ __launch_bounds__(256) void cur_gemm256(
    const ushort_t* __restrict__ Ah, const ushort_t* __restrict__ Al,
    const ushort_t* __restrict__ Wh, const ushort_t* __restrict__ Wl,
    const float* __restrict__ bias, float* __restrict__ C, int ldc)
{
    __shared__ ushort_t sAh[128 * 32];
    __shared__ ushort_t sAl[128 * 32];
    __shared__ ushort_t sWh[128 * 32];
    __shared__ ushort_t sWl[128 * 32];

    const int t = threadIdx.x;
    const int mBase = blockIdx.x * 128;
    const int nBase = blockIdx.y * 128;

    const int lane = t & 63;
    const int wv = t >> 6;
    const int wm = (wv & 1) * 64;
    const int wn = (wv >> 1) * 64;
    const int fr = lane & 15;
    const int fq = lane >> 4;

    const int r0 = t >> 2;               // 0..63
    const int cc = (t & 3) * 8;

    f32x4 acc[4][4];
#pragma unroll
    for (int i = 0; i < 4; i++)
#pragma unroll
        for (int j = 0; j < 4; j++) {
            f32x4 z = {0.f, 0.f, 0.f, 0.f};
            acc[i][j] = z;
        }

    for (int k0 = 0; k0 < 512; k0 += 32) {
        gload16(&Ah[(size_t)(mBase + r0) * 512 + k0 + cc], &sAh[t * 8]);
        gload16(&Ah[(size_t)(mBase + 64 + r0) * 512 + k0 + cc], &sAh[2048 + t * 8]);
        gload16(&Al[(size_t)(mBase + r0) * 512 + k0 + cc], &sAl[t * 8]);
        gload16(&Al[(size_t)(mBase + 64 + r0) * 512 + k0 + cc], &sAl[2048 + t * 8]);
        gload16(&Wh[(size_t)(nBase + r0) * 512 + k0 + cc], &sWh[t * 8]);
        gload16(&Wh[(size_t)(nBase + 64 + r0) * 512 + k0 + cc], &sWh[2048 + t * 8]);
        gload16(&Wl[(size_t)(nBase + r0) * 512 + k0 + cc], &sWl[t * 8]);
        gload16(&Wl[(size_t)(nBase + 64 + r0) * 512 + k0 + cc], &sWl[2048 + t * 8]);
        __syncthreads();

        bf16x8 af[4][2], wf[4][2];
#pragma unroll
        for (int i = 0; i < 4; i++) {
            af[i][0] = *(const bf16x8*)&sAh[(wm + i * 16 + fr) * 32 + fq * 8];
            af[i][1] = *(const bf16x8*)&sAl[(wm + i * 16 + fr) * 32 + fq * 8];
            wf[i][0] = *(const bf16x8*)&sWh[(wn + i * 16 + fr) * 32 + fq * 8];
            wf[i][1] = *(const bf16x8*)&sWl[(wn + i * 16 + fr) * 32 + fq * 8];
        }
#pragma unroll
        for (int i = 0; i < 4; i++)
#pragma unroll
            for (int j = 0; j < 4; j++) {
                acc[i][j] = __builtin_amdgcn_mfma_f32_16x16x32_bf16(af[i][0], wf[j][0], acc[i][j], 0, 0, 0);
                acc[i][j] = __builtin_amdgcn_mfma_f32_16x16x32_bf16(af[i][0], wf[j][1], acc[i][j], 0, 0, 0);
                acc[i][j] = __builtin_amdgcn_mfma_f32_16x16x32_bf16(af[i][1], wf[j][0], acc[i][j], 0, 0, 0);
            }
        __syncthreads();
    }

#pragma unroll
    for (int j = 0; j < 4; j++) {
        const int col = nBase + wn + j * 16 + fr;
        const float bv = bias[col];
#pragma unroll
        for (int i = 0; i < 4; i++)
#pragma unroll
            for (int r = 0; r < 4; r++) {
                const int row = mBase + wm + i * 16 + fq * 4 + r;
                C[(size_t)row * ldc + col] = acc[i][j][r] + bv;
            }
    }
}

// ---------------------------------------------------------------------------
// MLP GEMM: 64x128 tile, 256 threads = 4 waves side by side in n (per-wave
// 64x32, acc[4][2]).  512 blocks at M=2048,N=2048 -> 2 blocks/CU so one
// block's barrier drain overlaps the other's MFMA (m114 mechanism).
// Direct epilogue: bias + relu + bf16 store (no split-K partials/reduce).
// aHalfOff: block-diagonal A column offset for the upper n-half (layer 2).
// ---------------------------------------------------------------------------
__global__ __launch_bounds__(256) void mlp_gemm(
    const ushort_t* __restrict__ A, const ushort_t* __restrict__ W,
    const float* __restrict__ bias, ushort_t* __restrict__ C,
    int N, int K, int lda, int ldw, int ldc, int aHalfOff)
{
    __shared__ ushort_t sA[64 * 32];
    __shared__ ushort_t sW[128 * 32];

    const int t = threadIdx.x;
    const int mBase = blockIdx.x * 64;
    const int nBase = blockIdx.y * 128;
    const int aOff = (2 * nBase >= N) ? aHalfOff : 0;

    const int lane = t & 63;
    const int wv = t >> 6;
    const int wn = wv * 32;
    const int fr = lane & 15;
    const int fq = lane >> 4;

    const int r0 = t >> 2;               // 0..63
    const int cc = (t & 3) * 8;

    f32x4 acc[4][2];
#pragma unroll
    for (int i = 0; i < 4; i++)
#pragma unroll
        for (int j = 0; j < 2; j++) {
            f32x4 z = {0.f, 0.f, 0.f, 0.f};
            acc[i][j] = z;
        }

    for (int k0 = 0; k0 < K; k0 += 32) {
        gload16(&A[(size_t)(mBase + r0) * lda + aOff + k0 + cc], &sA[t * 8]);
        gload16(&W[(size_t)(nBase + r0) * ldw + k0 + cc], &sW[t * 8]);
        gload16(&W[(size_t)(nBase + 64 + r0) * ldw + k0 + cc], &sW[2048 + t * 8]);
        __syncthreads();

        bf16x8 af[4], wf[2];
#pragma unroll
        for (int i = 0; i < 4; i++)
            af[i] = *(const bf16x8*)&sA[(i * 16 + fr) * 32 + fq * 8];
#pragma unroll
        for (int j = 0; j < 2; j++)
            wf[j] = *(const bf16x8*)&sW[(wn + j * 16 + fr) * 32 + fq * 8];
#pragma unroll
        for (int i = 0; i < 4; i++)
#pragma unroll
            for (int j = 0; j < 2; j++)
                acc[i][j] = __builtin_amdgcn_mfma_f32_16x16x32_bf16(af[i], wf[j], acc[i][j], 0, 0, 0);
        __syncthreads();
    }

#pragma unroll
    for (int j = 0; j < 2; j++) {
        const int col = nBase + wn + j * 16 + fr;
        const float bv = bias[col];
#pragma unroll
        for (int i = 0; i < 4; i++)
#pragma unroll
            for (int r = 0; r < 4; r++) {
                const int row = mBase + i * 16 + fq * 4 + r;
                C[(size_t)row * ldc + col] = f2bf(fmaxf(acc[i][j][r] + bv, 0.f));
            }
    }
}

// ---------------------------------------------------------------------------
// LIF recurrence over 15 steps; cur: [B*5, 3072] fp32 (i1|i2|i3 per channel),
// writes x bf16 [2048, 4096] (col = c*4 + j).
// ---------------------------------------------------------------------------
__global__ __launch_bounds__(256) void recur_kernel(
    const float* __restrict__ cur, const float* __restrict__ wl,
    const float* __restrict__ bl, ushort_t* __restrict__ x)
{
    const int idx = blockIdx.x * 256 + threadIdx.x;
    const int b = idx >> 10, c = idx & 1023;
    const float wl0 = wl[0], wl1 = wl[1], wl2 = wl[2], bl0 = bl[0];
    float m0 = 0, m1 = 0, m2 = 0, m3 = 0;
    float s0 = 0, s1 = 0, s2 = 0, s3 = 0;
#pragma unroll
    for (int f = 0; f < 5; f++) {
        const float* p = cur + (size_t)(b * 5 + f) * 3072 + c;
        const float i1 = p[0], i2 = p[1024], i3 = p[2048];
#pragma unroll
        for (int rep = 0; rep < 3; rep++) {
            const float inner = m0 * wl0 + m1 * wl1 + m2 * wl2 + bl0;
            const float n0 = i1 + ((m0 > THRESH) ? 0.f : DECAY * m0);
            const float n1 = i2 + ((m1 > THRESH) ? 0.f : DECAY * m1);
            const float n2 = i3 + ((m2 > THRESH) ? 0.f : DECAY * m2);
            const float n3 = inner + ((m3 > THRESH) ? 0.f : DECAY * m3);
            m0 = n0; m1 = n1; m2 = n2; m3 = n3;
            s0 += (n0 > THRESH) ? 1.f : 0.f;
            s1 += (n1 > THRESH) ? 1.f : 0.f;
            s2 += (n2 > THRESH) ? 1.f : 0.f;
            s3 += (n3 > THRESH) ? 1.f : 0.f;
        }
    }
    const float inv = 1.f / 15.f;
    ushort4 o;
    o.x = f2bf(s0 * inv); o.y = f2bf(s1 * inv);
    o.z = f2bf(s2 * inv); o.w = f2bf(s3 * inv);
    *(ushort4*)&x[(size_t)b * 4096 + c * 4] = o;
}

// ---------------------------------------------------------------------------
// Consolidated prep (4 float4s per thread per segment block)
// ---------------------------------------------------------------------------
__device__ __forceinline__ void do_split4(const float4* src, ushort4* hi,
                                          ushort4* lo, int base, int t) {
#pragma unroll
    for (int p = 0; p < 4; p++) {
        const int i = base * 1024 + p * 256 + t;
        const float4 v = src[i];
        ushort4 h, l;
        h.x = f2bf(v.x); l.x = f2bf(v.x - bf2f(h.x));
        h.y = f2bf(v.y); l.y = f2bf(v.y - bf2f(h.y));
        h.z = f2bf(v.z); l.z = f2bf(v.z - bf2f(h.z));
        h.w = f2bf(v.w); l.w = f2bf(v.w - bf2f(h.w));
        hi[i] = h; lo[i] = l;
    }
}
__device__ __forceinline__ void do_cvt4(const float4* src, ushort4* dst,
                                        int base, int t) {
#pragma unroll
    for (int p = 0; p < 4; p++) {
        const int i = base * 1024 + p * 256 + t;
        const float4 v = src[i];
        ushort4 h;
        h.x = f2bf(v.x); h.y = f2bf(v.y); h.z = f2bf(v.z); h.w = f2bf(v.w);
        dst[i] = h;
    }
}

__global__ __launch_bounds__(256) void prep_kernel(
    const float* __restrict__ state,
    const float* __restrict__ w1, const float* __restrict__ w2,
    const float* __restrict__ w3,
    const float* __restrict__ w11, const float* __restrict__ w21,
    const float* __restrict__ w12, const float* __restrict__ w22,
    const float* __restrict__ b1, const float* __restrict__ b2,
    const float* __restrict__ b3, const float* __restrict__ b11,
    const float* __restrict__ b21, const float* __restrict__ b12,
    const float* __restrict__ b22,
    ushort_t* __restrict__ sh, ushort_t* __restrict__ sl,
    ushort_t* __restrict__ wh123, ushort_t* __restrict__ wl123,
    ushort_t* __restrict__ w1b, ushort_t* __restrict__ w2b,
    float* __restrict__ b123, float* __restrict__ bb1, float* __restrict__ bb2)
{
    const int bid = blockIdx.x;
    const int t = threadIdx.x;
    if (bid < 1280) {
        do_split4((const float4*)state, (ushort4*)sh, (ushort4*)sl, bid, t);
    } else if (bid < 1408) {
        do_split4((const float4*)w1, (ushort4*)wh123, (ushort4*)wl123, bid - 1280, t);
    } else if (bid < 1536) {
        do_split4((const float4*)w2, (ushort4*)(wh123 + 524288),
                  (ushort4*)(wl123 + 524288), bid - 1408, t);
    } else if (bid < 1664) {
        do_split4((const float4*)w3, (ushort4*)(wh123 + 1048576),
                  (ushort4*)(wl123 + 1048576), bid - 1536, t);
    } else if (bid < 2688) {
        do_cvt4((const float4*)w11, (ushort4*)w1b, bid - 1664, t);
    } else if (bid < 3712) {
        do_cvt4((const float4*)w21, (ushort4*)(w1b + 4194304), bid - 2688, t);
    } else if (bid < 3968) {
        do_cvt4((const float4*)w12, (ushort4*)w2b, bid - 3712, t);
    } else if (bid < 4224) {
        do_cvt4((const float4*)w22, (ushort4*)(w2b + 1048576), bid - 3968, t);
    } else {
#pragma unroll
        for (int p = 0; p < 4; p++) {
            const int i = p * 256 + t;
            b123[i] = b1[i]; b123[1024 + i] = b2[i]; b123[2048 + i] = b3[i];
            bb1[i] = b11[i]; bb1[1024 + i] = b21[i];
            bb2[i] = b12[i]; bb2[1024 + i] = b22[i];
        }
    }
}

// ---------------------------------------------------------------------------
// Heads (both branches): out[b][n] = (clip?)(h2[b][off+k] . w[n][k] + bias[n])
// ---------------------------------------------------------------------------
__global__ __launch_bounds__(256) void head_kernel(
    const ushort_t* __restrict__ h, const float* __restrict__ wm,
    const float* __restrict__ bm, const float* __restrict__ ws,
    const float* __restrict__ bs, float* __restrict__ out)
{
    const int t = threadIdx.x;
    const int branch = blockIdx.x >> 8;
    const int n = t & 31;
    const int b = (blockIdx.x & 255) * 8 + (t >> 5);
    const ushort_t* hr = h + (size_t)b * 2048 + branch * 1024;
    const float* wr = (branch ? ws : wm) + (size_t)n * 1024;
    float s = 0.f;
#pragma unroll 4
    for (int k = 0; k < 1024; k += 8) {
        const uint4 hv = *(const uint4*)&hr[k];
        const float4 w0 = *(const float4*)&wr[k];
        const float4 w1 = *(const float4*)&wr[k + 4];
        s += blo(hv.x) * w0.x + bhi(hv.x) * w0.y
           + blo(hv.y) * w0.z + bhi(hv.y) * w0.w
           + blo(hv.z) * w1.x + bhi(hv.z) * w1.y
           + blo(hv.w) * w1.z + bhi(hv.w) * w1.w;
    }
    s += (branch ? bs : bm)[n];
    if (branch) s = fminf(fmaxf(s, -20.f), 2.f);
    out[(size_t)branch * 65536 + (size_t)b * 32 + n] = s;
}

// ---------------------------------------------------------------------------
extern "C" void kernel_launch(void* const* d_in, const int* in_sizes, int n_in,
                              void* d_out, int out_size, void* d_ws, size_t ws_size,
                              hipStream_t stream)
{
    const float* state = (const float*)d_in[0];
    const float* w1  = (const float*)d_in[1];  const float* b1  = (const float*)d_in[2];
    const float* w2  = (const float*)d_in[3];  const float* b2  = (const float*)d_in[4];
    const float* w3  = (const float*)d_in[5];  const float* b3  = (const float*)d_in[6];
    const float* wl  = (const float*)d_in[7];  const float* bl  = (const float*)d_in[8];
    const float* w11 = (const float*)d_in[9];  const float* b11 = (const float*)d_in[10];
    const float* w12 = (const float*)d_in[11]; const float* b12 = (const float*)d_in[12];
    const float* w21 = (const float*)d_in[13]; const float* b21 = (const float*)d_in[14];
    const float* w22 = (const float*)d_in[15]; const float* b22 = (const float*)d_in[16];
    const float* wm  = (const float*)d_in[17]; const float* bm  = (const float*)d_in[18];
    const float* ws  = (const float*)d_in[19]; const float* bs  = (const float*)d_in[20];
    float* out = (float*)d_out;

    // ---- workspace layout ----
    char* wp = (char*)d_ws;
    float*    cur   = (float*)wp;     wp += (size_t)10240 * 3072 * 4;
    ushort_t* sh    = (ushort_t*)wp;  wp += (size_t)10240 * 512 * 2;
    ushort_t* sl    = (ushort_t*)wp;  wp += (size_t)10240 * 512 * 2;
    ushort_t* wh123 = (ushort_t*)wp;  wp += (size_t)3072 * 512 * 2;
    ushort_t* wl123 = (ushort_t*)wp;  wp += (size_t)3072 * 512 * 2;
    ushort_t* xb    = (ushort_t*)wp;  wp += (size_t)2048 * 4096 * 2;
    ushort_t* w1b   = (ushort_t*)wp;  wp += (size_t)2048 * 4096 * 2;
    ushort_t* w2b   = (ushort_t*)wp;  wp += (size_t)2048 * 1024 * 2;
    ushort_t* h1    = (ushort_t*)wp;  wp += (size_t)2048 * 2048 * 2;
    ushort_t* h2    = (ushort_t*)wp;  wp += (size_t)2048 * 2048 * 2;
    float*    b123  = (float*)wp;     wp += 3072 * 4;
    float*    bb1   = (float*)wp;     wp += 2048 * 4;
    float*    bb2   = (float*)wp;     wp += 2048 * 4;

    // ---- prep: all splits/cvts/bias packing in one launch ----
    prep_kernel<<<4225, 256, 0, stream>>>(
        state, w1, w2, w3, w11, w21, w12, w22,
        b1, b2, b3, b11, b21, b12, b22,
        sh, sl, wh123, wl123, w1b, w2b, b123, bb1, bb2);

    // ---- currents GEMM (3-term split): [10240,512] x [3072,512]^T -> cur ----
    cur_gemm256<<<dim3(80, 24), 256, 0, stream>>>(
        sh, sl, wh123, wl123, b123, cur, 3072);

    // ---- recurrence -> x bf16 [2048, 4096] ----
    recur_kernel<<<8192, 256, 0, stream>>>(cur, wl, bl, xb);

    // ---- MLP layer 1 (both branches, N=2048): 512 blocks, direct epilogue --
    mlp_gemm<<<dim3(32, 16), 256, 0, stream>>>(
        xb, w1b, bb1, h1, 2048, 4096, 4096, 4096, 2048, 0);

    // ---- MLP layer 2 (block-diagonal): 512 blocks, direct epilogue ----
    mlp_gemm<<<dim3(32, 16), 256, 0, stream>>>(
        h1, w2b, bb2, h2, 2048, 1024, 2048, 1024, 2048, 1024);

    // ---- heads (both branches) ----
    head_kernel<<<512, 256, 0, stream>>>(h2, wm, bm, ws, bs, out);
}

// Round 7
// 413.782 us; speedup vs baseline: 1.0906x; 1.0196x over previous
//
#include <hip/hip_runtime.h>
#include <cstddef>
#include <cstdint>

#define THRESH 0.8f
#define DECAY  0.2f

typedef unsigned short ushort_t;
typedef __attribute__((ext_vector_type(8))) short bf16x8;
typedef __attribute__((ext_vector_type(4))) float f32x4;

__device__ __forceinline__ ushort_t f2bf(float f) {
    union { float f; unsigned u; } v; v.f = f;
    unsigned r = v.u + 0x7FFFu + ((v.u >> 16) & 1u);
    return (ushort_t)(r >> 16);
}
__device__ __forceinline__ float bf2f(ushort_t h) {
    union { unsigned u; float f; } v; v.u = ((unsigned)h) << 16;
    return v.f;
}
__device__ __forceinline__ float blo(unsigned u) {
    union { unsigned x; float f; } v; v.x = u << 16; return v.f;
}
__device__ __forceinline__ float bhi(unsigned u) {
    union { unsigned x; float f; } v; v.x = u & 0xFFFF0000u; return v.f;
}

// async global->LDS, 16B per lane; LDS dest = wave-uniform base + lane*16
__device__ __forceinline__ void gload16(const void* g, void* l) {
    __builtin_amdgcn_global_load_lds(
        (const __attribute__((address_space(1))) void*)g,
        (__attribute__((address_space(3))) void*)l,
        16, 0, 0);
}

// ---------------------------------------------------------------------------
// Currents GEMM (measured-best shape, R2/R3: 104-106us): 512-thread (8-wave),
// 128x128 tile, BK=32, per-wave 64x32.  NSPLIT=3: hi*wh + hi*wl + lo*wh.
// ---------------------------------------------------------------------------
__global__ __launch_bounds__(512) void cur_gemm512(
    const ushort_t* __restrict__ Ah, const ushort_t* __restrict__ Al,
    const ushort_t* __restrict__ Wh, const ushort_t* __restrict__ Wl,
    const float* __restrict__ bias, float* __restrict__ C,
    int K, int ldc)
{
    __shared__ ushort_t sA[2][128 * 32];
    __shared__ ushort_t sW[2][128 * 32];

    const int t = threadIdx.x;
    const int mBase = blockIdx.x * 128;
    const int nBase = blockIdx.y * 128;

    const int lane = t & 63;
    const int wv = t >> 6;
    const int wm = (wv & 1) * 64;
    const int wn = (wv >> 1) * 32;
    const int fr = lane & 15;
    const int fq = lane >> 4;

    const int r0 = t >> 2;        // staging row 0..127
    const int cc = (t & 3) * 8;   // staging k-col

    f32x4 acc[4][2];
#pragma unroll
    for (int i = 0; i < 4; i++)
#pragma unroll
        for (int j = 0; j < 2; j++) {
            f32x4 z = {0.f, 0.f, 0.f, 0.f};
            acc[i][j] = z;
        }

    for (int k0 = 0; k0 < K; k0 += 32) {
        const int lin = t * 8;
        gload16(&Ah[(size_t)(mBase + r0) * K + k0 + cc], &sA[0][lin]);
        gload16(&Wh[(size_t)(nBase + r0) * K + k0 + cc], &sW[0][lin]);
        gload16(&Al[(size_t)(mBase + r0) * K + k0 + cc], &sA[1][lin]);
        gload16(&Wl[(size_t)(nBase + r0) * K + k0 + cc], &sW[1][lin]);
        __syncthreads();

        bf16x8 af[4][2], wf[2][2];
#pragma unroll
        for (int s = 0; s < 2; s++) {
#pragma unroll
            for (int i = 0; i < 4; i++)
                af[i][s] = *(const bf16x8*)&sA[s][(wm + i * 16 + fr) * 32 + fq * 8];
#pragma unroll
            for (int j = 0; j < 2; j++)
                wf[j][s] = *(const bf16x8*)&sW[s][(wn + j * 16 + fr) * 32 + fq * 8];
        }
#pragma unroll
        for (int i = 0; i < 4; i++)
#pragma unroll
            for (int j = 0; j < 2; j++) {
                acc[i][j] = __builtin_amdgcn_mfma_f32_16x16x32_bf16(af[i][0], wf[j][0], acc[i][j], 0, 0, 0);
                acc[i][j] = __builtin_amdgcn_mfma_f32_16x16x32_bf16(af[i][0], wf[j][1], acc[i][j], 0, 0, 0);
                acc[i][j] = __builtin_amdgcn_mfma_f32_16x16x32_bf16(af[i][1], wf[j][0], acc[i][j], 0, 0, 0);
            }
        __syncthreads();
    }

    // epilogue: C/D layout col=lane&15, row=(lane>>4)*4+reg
#pragma unroll
    for (int j = 0; j < 2; j++) {
        const int col = nBase + wn + j * 16 + fr;
        const float bv = bias[col];
#pragma unroll
        for (int i = 0; i < 4; i++)
#pragma unroll
            for (int r = 0; r < 4; r++) {
                const int row = mBase + wm + i * 16 + fq * 4 + r;
                C[(size_t)row * ldc + col] = acc[i][j][r] + bv;
            }
    }
}

// ---------------------------------------------------------------------------
// MLP GEMM: 256-thread (4-wave), 128x128 tile, per-wave 64x64 (4x4 frags),
// BK=32, plain bf16.  Split-K via blockIdx.z (K = per-slice length, partial
// fp32 out at C + z*sliceStride).  aHalfOff: block-diagonal A col offset.
// ---------------------------------------------------------------------------
__global__ __launch_bounds__(256) void mlp_gemm256(
    const ushort_t* __restrict__ A, const ushort_t* __restrict__ W,
    float* __restrict__ C,
    int N, int K, int lda, int ldw, int ldc, int aHalfOff,
    size_t sliceStride)
{
    __shared__ ushort_t sA[128 * 32];
    __shared__ ushort_t sW[128 * 32];

    const int t = threadIdx.x;
    const int mBase = blockIdx.x * 128;
    const int nBase = blockIdx.y * 128;
    const int kOff = blockIdx.z * K;
    const int aOff = (2 * nBase >= N) ? aHalfOff : 0;
    float* Cz = C + (size_t)blockIdx.z * sliceStride;

    const int lane = t & 63;
    const int wv = t >> 6;
    const int wm = (wv & 1) * 64;
    const int wn = (wv >> 1) * 64;
    const int fr = lane & 15;
    const int fq = lane >> 4;

    const int r0 = t >> 2;               // 0..63
    const int cc = (t & 3) * 8;

    f32x4 acc[4][4];
#pragma unroll
    for (int i = 0; i < 4; i++)
#pragma unroll
        for (int j = 0; j < 4; j++) {
            f32x4 z = {0.f, 0.f, 0.f, 0.f};
            acc[i][j] = z;
        }

    for (int k0 = 0; k0 < K; k0 += 32) {
        gload16(&A[(size_t)(mBase + r0) * lda + aOff + kOff + k0 + cc], &sA[t * 8]);
        gload16(&A[(size_t)(mBase + 64 + r0) * lda + aOff + kOff + k0 + cc], &sA[2048 + t * 8]);
        gload16(&W[(size_t)(nBase + r0) * ldw + kOff + k0 + cc], &sW[t * 8]);
        gload16(&W[(size_t)(nBase + 64 + r0) * ldw + kOff + k0 + cc], &sW[2048 + t * 8]);
        __syncthreads();

        bf16x8 af[4], wf[4];
#pragma unroll
        for (int i = 0; i < 4; i++) {
            af[i] = *(const bf16x8*)&sA[(wm + i * 16 + fr) * 32 + fq * 8];
            wf[i] = *(const bf16x8*)&sW[(wn + i * 16 + fr) * 32 + fq * 8];
        }
#pragma unroll
        for (int i = 0; i < 4; i++)
#pragma unroll
            for (int j = 0; j < 4; j++)
                acc[i][j] = __builtin_amdgcn_mfma_f32_16x16x32_bf16(af[i], wf[j], acc[i][j], 0, 0, 0);
        __syncthreads();
    }

#pragma unroll
    for (int j = 0; j < 4; j++) {
        const int col = nBase + wn + j * 16 + fr;
#pragma unroll
        for (int i = 0; i < 4; i++)
#pragma unroll
            for (int r = 0; r < 4; r++) {
                const int row = mBase + wm + i * 16 + fq * 4 + r;
                Cz[(size_t)row * ldc + col] = acc[i][j][r];
            }
    }
}

// ---------------------------------------------------------------------------
// split-K reduce: out_bf16[m][n] = relu(sum_s part[s][m][n] + bias[n])
// ---------------------------------------------------------------------------
template <int S>
__global__ __launch_bounds__(256) void reduce_relu(
    const float* __restrict__ part, const float* __restrict__ bias,
    ushort_t* __restrict__ out, int N, size_t MN)
{
    const size_t e = ((size_t)blockIdx.x * 256 + threadIdx.x) * 4;
    if (e >= MN) return;
    float4 a = *(const float4*)&part[e];
#pragma unroll
    for (int s = 1; s < S; s++) {
        const float4 b = *(const float4*)&part[s * MN + e];
        a.x += b.x; a.y += b.y; a.z += b.z; a.w += b.w;
    }
    const int n = (int)(e & (size_t)(N - 1));
    const float4 bv = *(const float4*)&bias[n];
    ushort4 o;
    o.x = f2bf(fmaxf(a.x + bv.x, 0.f));
    o.y = f2bf(fmaxf(a.y + bv.y, 0.f));
    o.z = f2bf(fmaxf(a.z + bv.z, 0.f));
    o.w = f2bf(fmaxf(a.w + bv.w, 0.f));
    *(ushort4*)&out[e] = o;
}

// ---------------------------------------------------------------------------
// LIF recurrence over 15 steps; cur: [B*5, 3072] fp32 (i1|i2|i3 per channel),
// writes x bf16 [2048, 4096] (col = c*4 + j).
// ---------------------------------------------------------------------------
__global__ __launch_bounds__(256) void recur_kernel(
    const float* __restrict__ cur, const float* __restrict__ wl,
    const float* __restrict__ bl, ushort_t* __restrict__ x)
{
    const int idx = blockIdx.x * 256 + threadIdx.x;
    const int b = idx >> 10, c = idx & 1023;
    const float wl0 = wl[0], wl1 = wl[1], wl2 = wl[2], bl0 = bl[0];
    float m0 = 0, m1 = 0, m2 = 0, m3 = 0;
    float s0 = 0, s1 = 0, s2 = 0, s3 = 0;
#pragma unroll
    for (int f = 0; f < 5; f++) {
        const float* p = cur + (size_t)(b * 5 + f) * 3072 + c;
        const float i1 = p[0], i2 = p[1024], i3 = p[2048];
#pragma unroll
        for (int rep = 0; rep < 3; rep++) {
            const float inner = m0 * wl0 + m1 * wl1 + m2 * wl2 + bl0;
            const float n0 = i1 + ((m0 > THRESH) ? 0.f : DECAY * m0);
            const float n1 = i2 + ((m1 > THRESH) ? 0.f : DECAY * m1);
            const float n2 = i3 + ((m2 > THRESH) ? 0.f : DECAY * m2);
            const float n3 = inner + ((m3 > THRESH) ? 0.f : DECAY * m3);
            m0 = n0; m1 = n1; m2 = n2; m3 = n3;
            s0 += (n0 > THRESH) ? 1.f : 0.f;
            s1 += (n1 > THRESH) ? 1.f : 0.f;
            s2 += (n2 > THRESH) ? 1.f : 0.f;
            s3 += (n3 > THRESH) ? 1.f : 0.f;
        }
    }
    const float inv = 1.f / 15.f;
    ushort4 o;
    o.x = f2bf(s0 * inv); o.y = f2bf(s1 * inv);
    o.z = f2bf(s2 * inv); o.w = f2bf(s3 * inv);
    *(ushort4*)&x[(size_t)b * 4096 + c * 4] = o;
}

// ---------------------------------------------------------------------------
// Consolidated prep (4 float4s per thread per segment block)
// ---------------------------------------------------------------------------
__device__ __forceinline__ void do_split4(const float4* src, ushort4* hi,
                                          ushort4* lo, int base, int t) {
#pragma unroll
    for (int p = 0; p < 4; p++) {
        const int i = base * 1024 + p * 256 + t;
        const float4 v = src[i];
        ushort4 h, l;
        h.x = f2bf(v.x); l.x = f2bf(v.x - bf2f(h.x));
        h.y = f2bf(v.y); l.y = f2bf(v.y - bf2f(h.y));
        h.z = f2bf(v.z); l.z = f2bf(v.z - bf2f(h.z));
        h.w = f2bf(v.w); l.w = f2bf(v.w - bf2f(h.w));
        hi[i] = h; lo[i] = l;
    }
}
__device__ __forceinline__ void do_cvt4(const float4* src, ushort4* dst,
                                        int base, int t) {
#pragma unroll
    for (int p = 0; p < 4; p++) {
        const int i = base * 1024 + p * 256 + t;
        const float4 v = src[i];
        ushort4 h;
        h.x = f2bf(v.x); h.y = f2bf(v.y); h.z = f2bf(v.z); h.w = f2bf(v.w);
        dst[i] = h;
    }
}

__global__ __launch_bounds__(256) void prep_kernel(
    const float* __restrict__ state,
    const float* __restrict__ w1, const float* __restrict__ w2,
    const float* __restrict__ w3,
    const float* __restrict__ w11, const float* __restrict__ w21,
    const float* __restrict__ w12, const float* __restrict__ w22,
    const float* __restrict__ b1, const float* __restrict__ b2,
    const float* __restrict__ b3, const float* __restrict__ b11,
    const float* __restrict__ b21, const float* __restrict__ b12,
    const float* __restrict__ b22,
    ushort_t* __restrict__ sh, ushort_t* __restrict__ sl,
    ushort_t* __restrict__ wh123, ushort_t* __restrict__ wl123,
    ushort_t* __restrict__ w1b, ushort_t* __restrict__ w2b,
    float* __restrict__ b123, float* __restrict__ bb1, float* __restrict__ bb2)
{
    const int bid = blockIdx.x;
    const int t = threadIdx.x;
    if (bid < 1280) {
        do_split4((const float4*)state, (ushort4*)sh, (ushort4*)sl, bid, t);
    } else if (bid < 1408) {
        do_split4((const float4*)w1, (ushort4*)wh123, (ushort4*)wl123, bid - 1280, t);
    } else if (bid < 1536) {
        do_split4((const float4*)w2, (ushort4*)(wh123 + 524288),
                  (ushort4*)(wl123 + 524288), bid - 1408, t);
    } else if (bid < 1664) {
        do_split4((const float4*)w3, (ushort4*)(wh123 + 1048576),
                  (ushort4*)(wl123 + 1048576), bid - 1536, t);
    } else if (bid < 2688) {
        do_cvt4((const float4*)w11, (ushort4*)w1b, bid - 1664, t);
    } else if (bid < 3712) {
        do_cvt4((const float4*)w21, (ushort4*)(w1b + 4194304), bid - 2688, t);
    } else if (bid < 3968) {
        do_cvt4((const float4*)w12, (ushort4*)w2b, bid - 3712, t);
    } else if (bid < 4224) {
        do_cvt4((const float4*)w22, (ushort4*)(w2b + 1048576), bid - 3968, t);
    } else {
#pragma unroll
        for (int p = 0; p < 4; p++) {
            const int i = p * 256 + t;
            b123[i] = b1[i]; b123[1024 + i] = b2[i]; b123[2048 + i] = b3[i];
            bb1[i] = b11[i]; bb1[1024 + i] = b21[i];
            bb2[i] = b12[i]; bb2[1024 + i] = b22[i];
        }
    }
}

// ---------------------------------------------------------------------------
// Heads (both branches): out[b][n] = (clip?)(h2[b][off+k] . w[n][k] + bias[n])
// ---------------------------------------------------------------------------
__global__ __launch_bounds__(256) void head_kernel(
    const ushort_t* __restrict__ h, const float* __restrict__ wm,
    const float* __restrict__ bm, const float* __restrict__ ws,
    const float* __restrict__ bs, float* __restrict__ out)
{
    const int t = threadIdx.x;
    const int branch = blockIdx.x >> 8;
    const int n = t & 31;
    const int b = (blockIdx.x & 255) * 8 + (t >> 5);
    const ushort_t* hr = h + (size_t)b * 2048 + branch * 1024;
    const float* wr = (branch ? ws : wm) + (size_t)n * 1024;
    float s = 0.f;
#pragma unroll 4
    for (int k = 0; k < 1024; k += 8) {
        const uint4 hv = *(const uint4*)&hr[k];
        const float4 w0 = *(const float4*)&wr[k];
        const float4 w1 = *(const float4*)&wr[k + 4];
        s += blo(hv.x) * w0.x + bhi(hv.x) * w0.y
           + blo(hv.y) * w0.z + bhi(hv.y) * w0.w
           + blo(hv.z) * w1.x + bhi(hv.z) * w1.y
           + blo(hv.w) * w1.z + bhi(hv.w) * w1.w;
    }
    s += (branch ? bs : bm)[n];
    if (branch) s = fminf(fmaxf(s, -20.f), 2.f);
    out[(size_t)branch * 65536 + (size_t)b * 32 + n] = s;
}

// ---------------------------------------------------------------------------
extern "C" void kernel_launch(void* const* d_in, const int* in_sizes, int n_in,
                              void* d_out, int out_size, void* d_ws, size_t ws_size,
                              hipStream_t stream)
{
    const float* state = (const float*)d_in[0];
    const float* w1  = (const float*)d_in[1];  const float* b1  = (const float*)d_in[2];
    const float* w2  = (const float*)d_in[3];  const float* b2  = (const float*)d_in[4];
    const float* w3  = (const float*)d_in[5];  const float* b3  = (const float*)d_in[6];
    const float* wl  = (const float*)d_in[7];  const float* bl  = (const float*)d_in[8];
    const float* w11 = (const float*)d_in[9];  const float* b11 = (const float*)d_in[10];
    const float* w12 = (const float*)d_in[11]; const float* b12 = (const float*)d_in[12];
    const float* w21 = (const float*)d_in[13]; const float* b21 = (const float*)d_in[14];
    const float* w22 = (const float*)d_in[15]; const float* b22 = (const float*)d_in[16];
    const float* wm  = (const float*)d_in[17]; const float* bm  = (const float*)d_in[18];
    const float* ws  = (const float*)d_in[19]; const float* bs  = (const float*)d_in[20];
    float* out = (float*)d_out;

    // ---- workspace layout (~208 MB) ----
    // cur (125.8 MB) doubles as the split-K partial buffer after recur consumes it
    char* wp = (char*)d_ws;
    float*    cur   = (float*)wp;     wp += (size_t)10240 * 3072 * 4;
    ushort_t* sh    = (ushort_t*)wp;  wp += (size_t)10240 * 512 * 2;
    ushort_t* sl    = (ushort_t*)wp;  wp += (size_t)10240 * 512 * 2;
    ushort_t* wh123 = (ushort_t*)wp;  wp += (size_t)3072 * 512 * 2;
    ushort_t* wl123 = (ushort_t*)wp;  wp += (size_t)3072 * 512 * 2;
    ushort_t* xb    = (ushort_t*)wp;  wp += (size_t)2048 * 4096 * 2;
    ushort_t* w1b   = (ushort_t*)wp;  wp += (size_t)2048 * 4096 * 2;
    ushort_t* w2b   = (ushort_t*)wp;  wp += (size_t)2048 * 1024 * 2;
    ushort_t* h1    = (ushort_t*)wp;  wp += (size_t)2048 * 2048 * 2;
    ushort_t* h2    = (ushort_t*)wp;  wp += (size_t)2048 * 2048 * 2;
    float*    b123  = (float*)wp;     wp += 3072 * 4;
    float*    bb1   = (float*)wp;     wp += 2048 * 4;
    float*    bb2   = (float*)wp;     wp += 2048 * 4;

    const size_t MN = (size_t)2048 * 2048;

    // ---- prep: all splits/cvts/bias packing in one launch ----
    prep_kernel<<<4225, 256, 0, stream>>>(
        state, w1, w2, w3, w11, w21, w12, w22,
        b1, b2, b3, b11, b21, b12, b22,
        sh, sl, wh123, wl123, w1b, w2b, b123, bb1, bb2);

    // ---- currents GEMM (3-term split): [10240,512] x [3072,512]^T -> cur ----
    cur_gemm512<<<dim3(80, 24), 512, 0, stream>>>(
        sh, sl, wh123, wl123, b123, cur, 512, 3072);

    // ---- recurrence -> x bf16 [2048, 4096] ----
    recur_kernel<<<8192, 256, 0, stream>>>(cur, wl, bl, xb);

    // ---- MLP layer 1 (both branches, N=2048), split-K=4 -> 1024 blocks ----
    mlp_gemm256<<<dim3(16, 16, 4), 256, 0, stream>>>(
        xb, w1b, cur, 2048, 1024, 4096, 4096, 2048, 0, MN);
    reduce_relu<4><<<4096, 256, 0, stream>>>(cur, bb1, h1, 2048, MN);

    // ---- MLP layer 2 (block-diagonal), split-K=2 -> 512 blocks ----
    mlp_gemm256<<<dim3(16, 16, 2), 256, 0, stream>>>(
        h1, w2b, cur, 2048, 512, 2048, 1024, 2048, 1024, MN);
    reduce_relu<2><<<4096, 256, 0, stream>>>(cur, bb2, h2, 2048, MN);

    // ---- heads (both branches) ----
    head_kernel<<<512, 256, 0, stream>>>(h2, wm, bm, ws, bs, out);
}